// Round 5
// baseline (307.525 us; speedup 1.0000x reference)
//
#include <hip/hip_runtime.h>
#include <stdint.h>

typedef unsigned short u16;
typedef __bf16 bf16x8 __attribute__((ext_vector_type(8)));
typedef float  f32x4  __attribute__((ext_vector_type(4)));
typedef int    i32x4  __attribute__((ext_vector_type(4)));

__device__ __forceinline__ u16 f2bf(float f){
  union{float f; uint32_t u;} v; v.f = f;
  uint32_t r = v.u + 0x7FFFu + ((v.u >> 16) & 1u);
  return (u16)(r >> 16);
}

#define GLDS16(gp, lp) __builtin_amdgcn_global_load_lds( \
    (const __attribute__((address_space(1))) void*)(gp),  \
    (__attribute__((address_space(3))) void*)(lp), 16, 0, 0)

// ---------------- fp32 -> bf16 convert (vectorized, grid-stride) ------------
__global__ __launch_bounds__(256) void cvt_kernel(const float* __restrict__ in,
                                                  u16* __restrict__ out, int n4) {
  int stride = gridDim.x * blockDim.x;
  for (int i = blockIdx.x * blockDim.x + threadIdx.x; i < n4; i += stride) {
    float4 v = ((const float4*)in)[i];
    u16 o0 = f2bf(v.x), o1 = f2bf(v.y), o2 = f2bf(v.z), o3 = f2bf(v.w);
    u16* p = out + (size_t)i * 4;
    uint32_t lo = (uint32_t)o0 | ((uint32_t)o1 << 16);
    uint32_t hi = (uint32_t)o2 | ((uint32_t)o3 << 16);
    ((uint2*)p)[0] = make_uint2(lo, hi);
  }
}

// ---------------- bf16 GEMM, C = A * B^T (+bias)(+resid) --------------------
template <int MODE>
__global__ __launch_bounds__(256) void gemm_bt(
    const u16* __restrict__ A, const u16* __restrict__ B,
    const float* __restrict__ bias,
    u16* __restrict__ Cbf, float* __restrict__ Cf, const float* __restrict__ resid,
    int M, int N, int K) {
  __shared__ u16 Alds[128 * 32];
  __shared__ u16 Blds[128 * 32];
  const int t = threadIdx.x;
  const int w = t >> 6, l = t & 63;
  const int wr = w >> 1, wc = w & 1;
  const int g = l >> 4, r16 = l & 15;

  // bijective XCD swizzle: contiguous grid chunk per XCD (nwg % 8 == 0)
  const int gx = gridDim.x;
  const int nwg = gx * gridDim.y;
  const int wg = blockIdx.y * gx + blockIdx.x;
  const int cpx = nwg >> 3;
  const int swz = (wg & 7) * cpx + (wg >> 3);
  const int brow = (swz / gx) * 128, bcol = (swz % gx) * 128;

  f32x4 acc[4][4];
#pragma unroll
  for (int mi = 0; mi < 4; mi++)
#pragma unroll
    for (int nj = 0; nj < 4; nj++) acc[mi][nj] = (f32x4){0.f, 0.f, 0.f, 0.f};

  const int c0 = 2 * w, c1 = 2 * w + 1;
  const int srow0 = c0 * 16 + (l >> 2);
  const int srow1 = c1 * 16 + (l >> 2);
  const int scol = (l & 3) * 8;

  for (int kt = 0; kt < K; kt += 32) {
    __syncthreads();
    GLDS16(A + (size_t)(brow + srow0) * K + kt + scol, (char*)Alds + c0 * 1024);
    GLDS16(A + (size_t)(brow + srow1) * K + kt + scol, (char*)Alds + c1 * 1024);
    GLDS16(B + (size_t)(bcol + srow0) * K + kt + scol, (char*)Blds + c0 * 1024);
    GLDS16(B + (size_t)(bcol + srow1) * K + kt + scol, (char*)Blds + c1 * 1024);
    __syncthreads();

    bf16x8 af[4], bfr[4];
#pragma unroll
    for (int mi = 0; mi < 4; mi++)
      af[mi] = *(const bf16x8*)&Alds[(wr * 64 + mi * 16 + r16) * 32 + g * 8];
#pragma unroll
    for (int nj = 0; nj < 4; nj++)
      bfr[nj] = *(const bf16x8*)&Blds[(wc * 64 + nj * 16 + r16) * 32 + g * 8];
#pragma unroll
    for (int mi = 0; mi < 4; mi++)
#pragma unroll
      for (int nj = 0; nj < 4; nj++)
        acc[mi][nj] = __builtin_amdgcn_mfma_f32_16x16x32_bf16(af[mi], bfr[nj], acc[mi][nj], 0, 0, 0);
  }

#pragma unroll
  for (int mi = 0; mi < 4; mi++) {
#pragma unroll
    for (int nj = 0; nj < 4; nj++) {
      int col = bcol + wc * 64 + nj * 16 + r16;
      float bv = bias[col];
#pragma unroll
      for (int rr = 0; rr < 4; rr++) {
        int row = brow + wr * 64 + mi * 16 + g * 4 + rr;
        float v = acc[mi][nj][rr] + bv;
        if (MODE == 0) {
          Cbf[(size_t)row * N + col] = f2bf(v);
        } else {
          v += resid[(size_t)row * N + col];
          Cf[(size_t)row * N + col] = v;
        }
      }
    }
  }
}

// ---------------- V transpose: qkv V-part -> vtg[b][h][64d][2048k] ----------
__global__ __launch_bounds__(256) void vtrans_kernel(const u16* __restrict__ qkv,
                                                     u16* __restrict__ vtg) {
  const int S = 2048, HD3 = 3072;
  __shared__ u16 Vs[64 * 64];
  const int st = blockIdx.x, h = blockIdx.y, b = blockIdx.z;
  const int t = threadIdx.x;
  const int s0 = st * 64;
#pragma unroll
  for (int i = 0; i < 2; i++) {
    int n = t + i * 256;
    int row = n >> 3, c = n & 7;
    const u16* src = qkv + ((size_t)(b * S) + s0 + row) * HD3 + 2048 + h * 64 + c * 8;
    i32x4 v = *(const i32x4*)src;
    *(i32x4*)&Vs[row * 64 + ((c ^ (row & 7)) << 3)] = v;
  }
  __syncthreads();
  const int d = t >> 2;
  const int dc = d >> 3, dl = d & 7;
#pragma unroll
  for (int i = 0; i < 2; i++) {
    int kc = (t & 3) + i * 4;
    u16 tmp[8];
#pragma unroll
    for (int j = 0; j < 8; j++) {
      int k = kc * 8 + j;
      tmp[j] = Vs[k * 64 + ((dc ^ (k & 7)) << 3) + dl];
    }
    *(i32x4*)(vtg + ((size_t)(b * 16 + h) * 64 + d) * S + s0 + kc * 8) = *(i32x4*)tmp;
  }
}

// ---------------- causal flash attention: 4 waves, 64-row q-tiles -----------
// Pairing over 32 q-tiles: block does qi = pair and 31-pair -> 33 K-tiles
// each, 1024 uniform blocks, 40 KB LDS -> 4 blocks/CU (exact fit).
__global__ __launch_bounds__(256) void attn_kernel(const u16* __restrict__ qkv,
                                                   const u16* __restrict__ vtg,
                                                   u16* __restrict__ ctxb) {
  const int S = 2048, HD3 = 3072;
  __shared__ u16 Kl[2][64 * 64];   // 16 KB
  __shared__ u16 Vl[2][64 * 64];   // 16 KB
  __shared__ u16 Pb[4][16 * 64];   // 8 KB (per-wave P buffer)

  const int h = blockIdx.x & 15, b = blockIdx.x >> 4;
  const int pair = blockIdx.y;  // 0..15 -> q-tiles qi=pair, 31-pair
  const int t = threadIdx.x, w = t >> 6, l = t & 63;
  const int g = l >> 4, r16 = l & 15;
  const size_t bS = (size_t)b * S;
  const size_t vbase = ((size_t)(b * 16 + h)) * 64 * S;

  // staging: 256 threads x 2 issues cover 64 rows x 8 swizzled 16B slots
  const int srow = t >> 3, ssl = t & 7;          // rows 0..31; +32 on issue 2
  const int scol = ((ssl ^ (srow & 7)) << 3);    // (srow+32)&7 == srow&7
  const int sdst = w * 1024;                     // wave-uniform LDS dest

  // hoisted LDS byte offsets (K/V fragment reads share the same pattern)
  int kfo[4][2], pwo[4][2], pro[2];
#pragma unroll
  for (int f = 0; f < 4; f++) {
    int row = f * 16 + r16;
#pragma unroll
    for (int c = 0; c < 2; c++)
      kfo[f][c] = (row * 64 + (((c * 4 + g) ^ (row & 7)) << 3)) * 2;
#pragma unroll
    for (int q2 = 0; q2 < 2; q2++) {
      int kidx = f * 16 + g * 4 + q2 * 2;
      pwo[f][q2] = r16 * 128 + (((kidx >> 3) ^ (r16 & 7)) << 4) + ((kidx & 7) << 1);
    }
  }
#pragma unroll
  for (int kh = 0; kh < 2; kh++)
    pro[kh] = r16 * 128 + (((kh * 4 + g) ^ (r16 & 7)) << 4);

  const float QSC = 0.125f * 1.44269504f;  // scores in log2 units
  char* PW = (char*)Pb + w * 2048;

#define STAGE(bi_)                                                            \
  do {                                                                        \
    GLDS16(kp, (char*)Kl + (bi_)*8192 + sdst);                                \
    GLDS16(kp + 32 * HD3, (char*)Kl + (bi_)*8192 + 4096 + sdst);              \
    GLDS16(vp, (char*)Vl + (bi_)*8192 + sdst);                                \
    GLDS16(vp + 32 * S, (char*)Vl + (bi_)*8192 + 4096 + sdst);                \
    kp += 64 * HD3; vp += 64;                                                 \
  } while (0)

  for (int seg = 0; seg < 2; seg++) {
    const int qi = seg ? (31 - pair) : pair;
    const int qmin = qi * 64 + w * 16;  // this wave's 16 q-rows
    const int nt = qi + 1;

    // Q fragments, pre-scaled into log2 domain
    const u16* qp = qkv + (bS + qmin + r16) * HD3 + h * 64 + g * 8;
    bf16x8 qf0 = *(const bf16x8*)qp;
    bf16x8 qf1 = *(const bf16x8*)(qp + 32);
#pragma unroll
    for (int j = 0; j < 8; j++) {
      qf0[j] = (__bf16)((float)qf0[j] * QSC);
      qf1[j] = (__bf16)((float)qf1[j] * QSC);
    }

    f32x4 ctx[4];
#pragma unroll
    for (int f = 0; f < 4; f++) ctx[f] = (f32x4){0.f, 0.f, 0.f, 0.f};
    float mrun = -1e30f, lrun = 0.f;

    const u16* kp = qkv + (bS + srow) * HD3 + 1024 + h * 64 + scol;
    const u16* vp = vtg + vbase + (size_t)srow * S + scol;

    __syncthreads();  // previous segment's readers done before LDS overwrite
    STAGE(0);
    int cur = 0;
    for (int kt = 0; kt < nt; kt++) {
      const int k0 = kt * 64;
      asm volatile("s_waitcnt vmcnt(0)" ::: "memory");
      __syncthreads();
      if (kt + 1 < nt) STAGE(cur ^ 1);

      const char* KB = (const char*)Kl + cur * 8192;
      const char* VB = (const char*)Vl + cur * 8192;

      // S^T (log2 units): lane holds S[k0+f*16+g*4+rr][qmin+r16]
      f32x4 sf[4];
      __builtin_amdgcn_s_setprio(1);
#pragma unroll
      for (int f = 0; f < 4; f++) {
        bf16x8 k0f = *(const bf16x8*)(KB + kfo[f][0]);
        bf16x8 k1f = *(const bf16x8*)(KB + kfo[f][1]);
        f32x4 s = (f32x4){0.f, 0.f, 0.f, 0.f};
        s = __builtin_amdgcn_mfma_f32_16x16x32_bf16(k0f, qf0, s, 0, 0, 0);
        s = __builtin_amdgcn_mfma_f32_16x16x32_bf16(k1f, qf1, s, 0, 0, 0);
        sf[f] = s;
      }
      __builtin_amdgcn_s_setprio(0);

      const int qg = qmin + r16;
      if (k0 + 64 > qmin) {  // diagonal tile: mask k > q
#pragma unroll
        for (int f = 0; f < 4; f++)
#pragma unroll
          for (int rr = 0; rr < 4; rr++)
            if (k0 + f * 16 + g * 4 + rr > qg) sf[f][rr] = -1e30f;
      }

      float tm = sf[0][0];
#pragma unroll
      for (int f = 0; f < 4; f++)
#pragma unroll
        for (int rr = 0; rr < 4; rr++) tm = fmaxf(tm, sf[f][rr]);
      tm = fmaxf(tm, __shfl_xor(tm, 16, 64));
      tm = fmaxf(tm, __shfl_xor(tm, 32, 64));

      const float mold = mrun;
      const bool skip = __all(tm <= mold + 8.0f);  // defer-max (log2 THR=8)
      const float mnew = skip ? mold : fmaxf(mold, tm);
      mrun = mnew;

      float p[4][4];
      float ps = 0.f;
#pragma unroll
      for (int f = 0; f < 4; f++)
#pragma unroll
        for (int rr = 0; rr < 4; rr++) {
          p[f][rr] = exp2f(sf[f][rr] - mnew);
          ps += p[f][rr];
        }
      ps += __shfl_xor(ps, 16, 64);
      ps += __shfl_xor(ps, 32, 64);

      if (skip) {
        lrun += ps;
      } else {
        float sc = exp2f(mold - mnew);
        lrun = lrun * sc + ps;
#pragma unroll
        for (int rr = 0; rr < 4; rr++) {
          float scq = __shfl(sc, g * 4 + rr, 64);
#pragma unroll
          for (int f = 0; f < 4; f++) ctx[f][rr] *= scq;
        }
      }

      // P^T -> per-wave swizzled Pb (packed bf16 pairs)
#pragma unroll
      for (int f = 0; f < 4; f++)
#pragma unroll
        for (int q2 = 0; q2 < 2; q2++) {
          union { __bf16 b; u16 u; } a0, a1;
          a0.b = (__bf16)p[f][q2 * 2];
          a1.b = (__bf16)p[f][q2 * 2 + 1];
          *(uint32_t*)(PW + pwo[f][q2]) = (uint32_t)a0.u | ((uint32_t)a1.u << 16);
        }

      bf16x8 pf[2];
#pragma unroll
      for (int kh = 0; kh < 2; kh++) pf[kh] = *(const bf16x8*)(PW + pro[kh]);
      __builtin_amdgcn_s_setprio(1);
#pragma unroll
      for (int f = 0; f < 4; f++)
#pragma unroll
        for (int kh = 0; kh < 2; kh++) {
          bf16x8 vf = *(const bf16x8*)(VB + kfo[f][kh]);
          ctx[f] = __builtin_amdgcn_mfma_f32_16x16x32_bf16(pf[kh], vf, ctx[f], 0, 0, 0);
        }
      __builtin_amdgcn_s_setprio(0);
      cur ^= 1;
    }

    // epilogue: lane holds ctx[q=qmin+g*4+rr][d=f*16+r16]
    float linv = 1.f / lrun;
#pragma unroll
    for (int rr = 0; rr < 4; rr++) {
      float li = __shfl(linv, g * 4 + rr, 64);
      int qg = qmin + g * 4 + rr;
#pragma unroll
      for (int f = 0; f < 4; f++) {
        union { __bf16 b; u16 u; } o;
        o.b = (__bf16)(ctx[f][rr] * li);
        ctxb[(bS + qg) * 1024 + h * 64 + f * 16 + r16] = o.u;
      }
    }
  }
#undef STAGE
}

// ---------------- in-place LayerNorm over rows of 1024 ----------------------
__global__ __launch_bounds__(256) void ln_kernel(float* __restrict__ y,
                                                 const float* __restrict__ gamma,
                                                 const float* __restrict__ beta) {
  __shared__ float sh[4];
  const int row = blockIdx.x, t = threadIdx.x;
  const int w = t >> 6, l = t & 63;
  float4 v = ((const float4*)(y + (size_t)row * 1024))[t];
  float s = v.x + v.y + v.z + v.w;
#pragma unroll
  for (int m = 32; m; m >>= 1) s += __shfl_xor(s, m, 64);
  if (l == 0) sh[w] = s;
  __syncthreads();
  float mu = (sh[0] + sh[1] + sh[2] + sh[3]) * (1.0f / 1024.0f);
  float dx = v.x - mu, dy = v.y - mu, dz = v.z - mu, dw = v.w - mu;
  float ss = dx * dx + dy * dy + dz * dz + dw * dw;
#pragma unroll
  for (int m = 32; m; m >>= 1) ss += __shfl_xor(ss, m, 64);
  __syncthreads();
  if (l == 0) sh[w] = ss;
  __syncthreads();
  float var = (sh[0] + sh[1] + sh[2] + sh[3]) * (1.0f / 1024.0f);
  float rs = rsqrtf(var + 1e-5f);
  float4 gm = ((const float4*)gamma)[t];
  float4 bt = ((const float4*)beta)[t];
  float4 o;
  o.x = dx * rs * gm.x + bt.x;
  o.y = dy * rs * gm.y + bt.y;
  o.z = dz * rs * gm.z + bt.z;
  o.w = dw * rs * gm.w + bt.w;
  ((float4*)(y + (size_t)row * 1024))[t] = o;
}

// ---------------- launcher ---------------------------------------------------
extern "C" void kernel_launch(void* const* d_in, const int* in_sizes, int n_in,
                              void* d_out, int out_size, void* d_ws, size_t ws_size,
                              hipStream_t stream) {
  (void)in_sizes; (void)n_in; (void)out_size; (void)ws_size;
  const float* x     = (const float*)d_in[0];
  const float* w1    = (const float*)d_in[1];
  const float* b1    = (const float*)d_in[2];
  const float* w2    = (const float*)d_in[3];
  const float* b2    = (const float*)d_in[4];
  const float* gamma = (const float*)d_in[5];
  const float* beta  = (const float*)d_in[6];
  float* out = (float*)d_out;

  const int M = 8192, D = 1024, N1 = 3072;

  char* ws = (char*)d_ws;
  u16* x_bf   = (u16*)(ws);                 // 16 MB; dead after gemm1
  u16* w1_bf  = (u16*)(ws + 16777216);
  u16* w2_bf  = (u16*)(ws + 23068672);
  u16* qkv_bf = (u16*)(ws + 25165824);      // 50 MB
  u16* ctx_bf = (u16*)(ws + 75497472);      // 16 MB
  u16* vtg    = (u16*)(ws);                 // reuses x_bf region (16 MB)

  cvt_kernel<<<2048, 256, 0, stream>>>(x, x_bf, M * D / 4);
  cvt_kernel<<<1024, 256, 0, stream>>>(w1, w1_bf, N1 * D / 4);
  cvt_kernel<<<512, 256, 0, stream>>>(w2, w2_bf, D * D / 4);

  gemm_bt<0><<<dim3(N1 / 128, M / 128), 256, 0, stream>>>(
      x_bf, w1_bf, b1, qkv_bf, nullptr, nullptr, M, N1, D);

  vtrans_kernel<<<dim3(32, 16, 4), 256, 0, stream>>>(qkv_bf, vtg);

  // grid: x = b*16+h (64), y = pair (16); wg%8 == bh%8 -> same-bh same-XCD
  attn_kernel<<<dim3(64, 16), 256, 0, stream>>>(qkv_bf, vtg, ctx_bf);

  gemm_bt<1><<<dim3(D / 128, M / 128), 256, 0, stream>>>(
      ctx_bf, w2_bf, b2, nullptr, out, x, M, D, D);

  ln_kernel<<<M, 256, 0, stream>>>(out, gamma, beta);
}

// Round 6
// 283.455 us; speedup vs baseline: 1.0849x; 1.0849x over previous
//
#include <hip/hip_runtime.h>
#include <stdint.h>

typedef unsigned short u16;
typedef __bf16 bf16x8 __attribute__((ext_vector_type(8)));
typedef float  f32x4  __attribute__((ext_vector_type(4)));
typedef float  f32x16 __attribute__((ext_vector_type(16)));
typedef int    i32x4  __attribute__((ext_vector_type(4)));

__device__ __forceinline__ u16 f2bf(float f){
  union{float f; uint32_t u;} v; v.f = f;
  uint32_t r = v.u + 0x7FFFu + ((v.u >> 16) & 1u);
  return (u16)(r >> 16);
}

__device__ __forceinline__ uint32_t cvtpk(float a, float b){
  uint32_t r;
  asm("v_cvt_pk_bf16_f32 %0, %1, %2" : "=v"(r) : "v"(a), "v"(b));
  return r;
}

#define GLDS16(gp, lp) __builtin_amdgcn_global_load_lds( \
    (const __attribute__((address_space(1))) void*)(gp),  \
    (__attribute__((address_space(3))) void*)(lp), 16, 0, 0)

// ---------------- fp32 -> bf16 convert (vectorized, grid-stride) ------------
__global__ __launch_bounds__(256) void cvt_kernel(const float* __restrict__ in,
                                                  u16* __restrict__ out, int n4) {
  int stride = gridDim.x * blockDim.x;
  for (int i = blockIdx.x * blockDim.x + threadIdx.x; i < n4; i += stride) {
    float4 v = ((const float4*)in)[i];
    u16 o0 = f2bf(v.x), o1 = f2bf(v.y), o2 = f2bf(v.z), o3 = f2bf(v.w);
    u16* p = out + (size_t)i * 4;
    uint32_t lo = (uint32_t)o0 | ((uint32_t)o1 << 16);
    uint32_t hi = (uint32_t)o2 | ((uint32_t)o3 << 16);
    ((uint2*)p)[0] = make_uint2(lo, hi);
  }
}

// ---------------- bf16 GEMM, C = A * B^T (+bias)(+resid) --------------------
template <int MODE>
__global__ __launch_bounds__(256) void gemm_bt(
    const u16* __restrict__ A, const u16* __restrict__ B,
    const float* __restrict__ bias,
    u16* __restrict__ Cbf, float* __restrict__ Cf, const float* __restrict__ resid,
    int M, int N, int K) {
  __shared__ u16 Alds[128 * 32];
  __shared__ u16 Blds[128 * 32];
  const int t = threadIdx.x;
  const int w = t >> 6, l = t & 63;
  const int wr = w >> 1, wc = w & 1;
  const int g = l >> 4, r16 = l & 15;

  const int gx = gridDim.x;
  const int nwg = gx * gridDim.y;
  const int wg = blockIdx.y * gx + blockIdx.x;
  const int cpx = nwg >> 3;
  const int swz = (wg & 7) * cpx + (wg >> 3);
  const int brow = (swz / gx) * 128, bcol = (swz % gx) * 128;

  f32x4 acc[4][4];
#pragma unroll
  for (int mi = 0; mi < 4; mi++)
#pragma unroll
    for (int nj = 0; nj < 4; nj++) acc[mi][nj] = (f32x4){0.f, 0.f, 0.f, 0.f};

  const int c0 = 2 * w, c1 = 2 * w + 1;
  const int srow0 = c0 * 16 + (l >> 2);
  const int srow1 = c1 * 16 + (l >> 2);
  const int scol = (l & 3) * 8;

  for (int kt = 0; kt < K; kt += 32) {
    __syncthreads();
    GLDS16(A + (size_t)(brow + srow0) * K + kt + scol, (char*)Alds + c0 * 1024);
    GLDS16(A + (size_t)(brow + srow1) * K + kt + scol, (char*)Alds + c1 * 1024);
    GLDS16(B + (size_t)(bcol + srow0) * K + kt + scol, (char*)Blds + c0 * 1024);
    GLDS16(B + (size_t)(bcol + srow1) * K + kt + scol, (char*)Blds + c1 * 1024);
    __syncthreads();

    bf16x8 af[4], bfr[4];
#pragma unroll
    for (int mi = 0; mi < 4; mi++)
      af[mi] = *(const bf16x8*)&Alds[(wr * 64 + mi * 16 + r16) * 32 + g * 8];
#pragma unroll
    for (int nj = 0; nj < 4; nj++)
      bfr[nj] = *(const bf16x8*)&Blds[(wc * 64 + nj * 16 + r16) * 32 + g * 8];
#pragma unroll
    for (int mi = 0; mi < 4; mi++)
#pragma unroll
      for (int nj = 0; nj < 4; nj++)
        acc[mi][nj] = __builtin_amdgcn_mfma_f32_16x16x32_bf16(af[mi], bfr[nj], acc[mi][nj], 0, 0, 0);
  }

#pragma unroll
  for (int mi = 0; mi < 4; mi++) {
#pragma unroll
    for (int nj = 0; nj < 4; nj++) {
      int col = bcol + wc * 64 + nj * 16 + r16;
      float bv = bias[col];
#pragma unroll
      for (int rr = 0; rr < 4; rr++) {
        int row = brow + wr * 64 + mi * 16 + g * 4 + rr;
        float v = acc[mi][nj][rr] + bv;
        if (MODE == 0) {
          Cbf[(size_t)row * N + col] = f2bf(v);
        } else {
          v += resid[(size_t)row * N + col];
          Cf[(size_t)row * N + col] = v;
        }
      }
    }
  }
}

// ---------------- V transpose: qkv V-part -> vtg[b][h][64d][2048k] ----------
__global__ __launch_bounds__(256) void vtrans_kernel(const u16* __restrict__ qkv,
                                                     u16* __restrict__ vtg) {
  const int S = 2048, HD3 = 3072;
  __shared__ u16 Vs[64 * 64];
  const int st = blockIdx.x, h = blockIdx.y, b = blockIdx.z;
  const int t = threadIdx.x;
  const int s0 = st * 64;
#pragma unroll
  for (int i = 0; i < 2; i++) {
    int n = t + i * 256;
    int row = n >> 3, c = n & 7;
    const u16* src = qkv + ((size_t)(b * S) + s0 + row) * HD3 + 2048 + h * 64 + c * 8;
    i32x4 v = *(const i32x4*)src;
    *(i32x4*)&Vs[row * 64 + ((c ^ (row & 7)) << 3)] = v;
  }
  __syncthreads();
  const int d = t >> 2;
  const int dc = d >> 3, dl = d & 7;
#pragma unroll
  for (int i = 0; i < 2; i++) {
    int kc = (t & 3) + i * 4;
    u16 tmp[8];
#pragma unroll
    for (int j = 0; j < 8; j++) {
      int k = kc * 8 + j;
      tmp[j] = Vs[k * 64 + ((dc ^ (k & 7)) << 3) + dl];
    }
    *(i32x4*)(vtg + ((size_t)(b * 16 + h) * 64 + d) * S + s0 + kc * 8) = *(i32x4*)tmp;
  }
}

// ------- causal flash attention: 32x32 MFMA, in-register softmax (T12) ------
// 4 waves/block, wave owns 32 q-rows (QBLK=128, KVBLK=64).
// qkv: [B*S][3072] bf16. vtg: [b][h][64][2048] bf16 (V^T). ctxb: bf16 out.
__global__ __launch_bounds__(256) void attn_kernel(const u16* __restrict__ qkv,
                                                   const u16* __restrict__ vtg,
                                                   u16* __restrict__ ctxb) {
  const int S = 2048, HD3 = 3072;
  __shared__ u16 Kl[2][64 * 64];   // 16 KB (rows k, cols hd, swizzled slots)
  __shared__ u16 Vl[2][64 * 64];   // 16 KB (rows d, cols k, swizzled slots)

  const int h = blockIdx.x & 15, b = blockIdx.x >> 4;
  const int qi = 15 - (int)blockIdx.y;       // reversed: longest first
  const int t = threadIdx.x, w = t >> 6, l = t & 63;
  const int l31 = l & 31, hi = l >> 5;
  const size_t bS = (size_t)b * S;
  const size_t vbase = ((size_t)(b * 16 + h)) * 64 * S;

  // staging: 256 threads x (2 K + 2 V) issues cover 64 rows x 8 slots each
  const int srow = t >> 3, ssl = t & 7;
  const int scol = ((ssl ^ (srow & 7)) << 3);
  const int sdst = w * 1024;

  // fragment-read byte offsets (row l31, +32ks / +32dt via *4096)
  int kro[4], vro[2][2];
#pragma unroll
  for (int hs = 0; hs < 4; hs++)
    kro[hs] = l31 * 128 + (((2 * hs + hi) ^ (l31 & 7)) << 4);
#pragma unroll
  for (int ks = 0; ks < 2; ks++)
#pragma unroll
    for (int s2 = 0; s2 < 2; s2++)
      vro[ks][s2] = l31 * 128 + (((ks * 4 + s2 * 2 + hi) ^ (l31 & 7)) << 4);

  const float QSC = 0.125f * 1.44269504f;  // scores in log2 units
  const int q0w = qi * 128 + w * 32;       // wave's 32 q-rows
  const int qv = q0w + l31;                // this lane's q
  const int nt = 2 * qi + 2;

  // Q fragments (B-operand): lane holds Q[qv][hs*16 + hi*8 + j], log2-scaled
  bf16x8 qfr[4];
  {
    const u16* qp = qkv + (bS + qv) * HD3 + h * 64 + hi * 8;
#pragma unroll
    for (int hs = 0; hs < 4; hs++) {
      bf16x8 a = *(const bf16x8*)(qp + hs * 16);
#pragma unroll
      for (int j = 0; j < 8; j++) a[j] = (__bf16)((float)a[j] * QSC);
      qfr[hs] = a;
    }
  }

  f32x16 o[2];
  o[0] = (f32x16)(0.f); o[1] = (f32x16)(0.f);
  float mrun = -1e30f, lrun = 0.f;

  const u16* kp = qkv + (bS + srow) * HD3 + 1024 + h * 64 + scol;
  const u16* vp = vtg + vbase + (size_t)srow * S + scol;

#define STAGE(bi_)                                                            \
  do {                                                                        \
    GLDS16(kp, (char*)Kl + (bi_)*8192 + sdst);                                \
    GLDS16(kp + 32 * HD3, (char*)Kl + (bi_)*8192 + 4096 + sdst);              \
    GLDS16(vp, (char*)Vl + (bi_)*8192 + sdst);                                \
    GLDS16(vp + 32 * S, (char*)Vl + (bi_)*8192 + 4096 + sdst);                \
    kp += 64 * HD3; vp += 64;                                                 \
  } while (0)

  STAGE(0);
  int cur = 0;
  for (int kt = 0; kt < nt; kt++) {
    const int k0 = kt * 64;
    asm volatile("s_waitcnt vmcnt(0)" ::: "memory");
    __syncthreads();
    if (kt + 1 < nt) STAGE(cur ^ 1);

    if (k0 < q0w + 32) {  // wave participates
      const char* KB = (const char*)Kl + cur * 8192;
      const char* VB = (const char*)Vl + cur * 8192;

      // QK^T: s[ks] holds S^T[k0+32ks+kloc(r,hi)][qv] in log2 units
      f32x16 s[2];
      __builtin_amdgcn_s_setprio(1);
#pragma unroll
      for (int ks = 0; ks < 2; ks++) {
        f32x16 a = (f32x16)(0.f);
#pragma unroll
        for (int hs = 0; hs < 4; hs++) {
          bf16x8 kf = *(const bf16x8*)(KB + ks * 4096 + kro[hs]);
          a = __builtin_amdgcn_mfma_f32_32x32x16_bf16(kf, qfr[hs], a, 0, 0, 0);
        }
        s[ks] = a;
      }
      __builtin_amdgcn_s_setprio(0);

      if (k0 + 63 > q0w) {  // diagonal: mask k > q
#pragma unroll
        for (int ks = 0; ks < 2; ks++)
#pragma unroll
          for (int r = 0; r < 16; r++) {
            int kg = k0 + ks * 32 + ((r & 3) + 8 * (r >> 2) + 4 * hi);
            if (kg > qv) s[ks][r] = -1e30f;
          }
      }

      // row max over 64 k (lane pair l, l^32)
      float tm = s[0][0];
#pragma unroll
      for (int ks = 0; ks < 2; ks++)
#pragma unroll
        for (int r = 0; r < 16; r++) tm = fmaxf(tm, s[ks][r]);
      tm = fmaxf(tm, __shfl_xor(tm, 32, 64));

      const float mold = mrun;
      const bool skip = __all(tm <= mold + 8.0f);  // defer-max (log2 THR=8)
      const float mnew = skip ? mold : fmaxf(mold, tm);
      mrun = mnew;

      float ps = 0.f;
#pragma unroll
      for (int ks = 0; ks < 2; ks++)
#pragma unroll
        for (int r = 0; r < 16; r++) {
          float e = __builtin_amdgcn_exp2f(s[ks][r] - mnew);
          s[ks][r] = e;
          ps += e;
        }
      ps += __shfl_xor(ps, 32, 64);

      if (skip) {
        lrun += ps;
      } else {
        float sc = __builtin_amdgcn_exp2f(mold - mnew);
        lrun = lrun * sc + ps;
#pragma unroll
        for (int dt = 0; dt < 2; dt++)
#pragma unroll
          for (int r = 0; r < 16; r++) o[dt][r] *= sc;
      }

      // pack P -> PV B-fragments in-register (cvt_pk + permlane32_swap)
#pragma unroll
      for (int ks = 0; ks < 2; ks++) {
        uint32_t wk0 = cvtpk(s[ks][0],  s[ks][1]);
        uint32_t wk1 = cvtpk(s[ks][2],  s[ks][3]);
        uint32_t wk2 = cvtpk(s[ks][4],  s[ks][5]);
        uint32_t wk3 = cvtpk(s[ks][6],  s[ks][7]);
        uint32_t wk4 = cvtpk(s[ks][8],  s[ks][9]);
        uint32_t wk5 = cvtpk(s[ks][10], s[ks][11]);
        uint32_t wk6 = cvtpk(s[ks][12], s[ks][13]);
        uint32_t wk7 = cvtpk(s[ks][14], s[ks][15]);
        asm("v_permlane32_swap_b32 %0, %1" : "+v"(wk0), "+v"(wk2));
        asm("v_permlane32_swap_b32 %0, %1" : "+v"(wk1), "+v"(wk3));
        asm("v_permlane32_swap_b32 %0, %1" : "+v"(wk4), "+v"(wk6));
        asm("v_permlane32_swap_b32 %0, %1" : "+v"(wk5), "+v"(wk7));
        union { uint32_t u[4]; bf16x8 v; } p0, p1;
        p0.u[0] = wk0; p0.u[1] = wk1; p0.u[2] = wk2; p0.u[3] = wk3;
        p1.u[0] = wk4; p1.u[1] = wk5; p1.u[2] = wk6; p1.u[3] = wk7;

        __builtin_amdgcn_s_setprio(1);
#pragma unroll
        for (int dt = 0; dt < 2; dt++) {
          bf16x8 vf0 = *(const bf16x8*)(VB + dt * 4096 + vro[ks][0]);
          bf16x8 vf1 = *(const bf16x8*)(VB + dt * 4096 + vro[ks][1]);
          o[dt] = __builtin_amdgcn_mfma_f32_32x32x16_bf16(vf0, p0.v, o[dt], 0, 0, 0);
          o[dt] = __builtin_amdgcn_mfma_f32_32x32x16_bf16(vf1, p1.v, o[dt], 0, 0, 0);
        }
        __builtin_amdgcn_s_setprio(0);
      }
    }
    cur ^= 1;
  }

  // epilogue: O^T[d][qv] in o[dt][r]; bounce via free LDS buffer, store rows
  {
    float linv = 1.f / lrun;
    char* Ob = ((w < 2) ? (char*)Kl : (char*)Vl) + cur * 8192 + (w & 1) * 4096;
#pragma unroll
    for (int dt = 0; dt < 2; dt++)
#pragma unroll
      for (int i = 0; i < 8; i++) {
        uint32_t pk = cvtpk(o[dt][2 * i] * linv, o[dt][2 * i + 1] * linv);
        int d = dt * 32 + 8 * (i >> 1) + 2 * (i & 1) + 4 * hi;
        int c8 = d >> 3;
        *(uint32_t*)(Ob + l31 * 128 + ((c8 ^ (l31 & 7)) << 4) + ((d & 7) << 1)) = pk;
      }
    asm volatile("s_waitcnt lgkmcnt(0)" ::: "memory");
#pragma unroll
    for (int bq = 0; bq < 4; bq++) {
      int qr = bq * 8 + (l >> 3);
      int c = l & 7;
      i32x4 vvv = *(const i32x4*)(Ob + qr * 128 + ((c ^ (qr & 7)) << 4));
      *(i32x4*)(ctxb + (bS + q0w + qr) * 1024 + h * 64 + c * 8) = vvv;
    }
  }
#undef STAGE
}

// ---------------- in-place LayerNorm over rows of 1024 ----------------------
__global__ __launch_bounds__(256) void ln_kernel(float* __restrict__ y,
                                                 const float* __restrict__ gamma,
                                                 const float* __restrict__ beta) {
  __shared__ float sh[4];
  const int row = blockIdx.x, t = threadIdx.x;
  const int w = t >> 6, l = t & 63;
  float4 v = ((const float4*)(y + (size_t)row * 1024))[t];
  float s = v.x + v.y + v.z + v.w;
#pragma unroll
  for (int m = 32; m; m >>= 1) s += __shfl_xor(s, m, 64);
  if (l == 0) sh[w] = s;
  __syncthreads();
  float mu = (sh[0] + sh[1] + sh[2] + sh[3]) * (1.0f / 1024.0f);
  float dx = v.x - mu, dy = v.y - mu, dz = v.z - mu, dw = v.w - mu;
  float ss = dx * dx + dy * dy + dz * dz + dw * dw;
#pragma unroll
  for (int m = 32; m; m >>= 1) ss += __shfl_xor(ss, m, 64);
  __syncthreads();
  if (l == 0) sh[w] = ss;
  __syncthreads();
  float var = (sh[0] + sh[1] + sh[2] + sh[3]) * (1.0f / 1024.0f);
  float rs = rsqrtf(var + 1e-5f);
  float4 gm = ((const float4*)gamma)[t];
  float4 bt = ((const float4*)beta)[t];
  float4 o;
  o.x = dx * rs * gm.x + bt.x;
  o.y = dy * rs * gm.y + bt.y;
  o.z = dz * rs * gm.z + bt.z;
  o.w = dw * rs * gm.w + bt.w;
  ((float4*)(y + (size_t)row * 1024))[t] = o;
}

// ---------------- launcher ---------------------------------------------------
extern "C" void kernel_launch(void* const* d_in, const int* in_sizes, int n_in,
                              void* d_out, int out_size, void* d_ws, size_t ws_size,
                              hipStream_t stream) {
  (void)in_sizes; (void)n_in; (void)out_size; (void)ws_size;
  const float* x     = (const float*)d_in[0];
  const float* w1    = (const float*)d_in[1];
  const float* b1    = (const float*)d_in[2];
  const float* w2    = (const float*)d_in[3];
  const float* b2    = (const float*)d_in[4];
  const float* gamma = (const float*)d_in[5];
  const float* beta  = (const float*)d_in[6];
  float* out = (float*)d_out;

  const int M = 8192, D = 1024, N1 = 3072;

  char* ws = (char*)d_ws;
  u16* x_bf   = (u16*)(ws);                 // 16 MB; dead after gemm1
  u16* w1_bf  = (u16*)(ws + 16777216);
  u16* w2_bf  = (u16*)(ws + 23068672);
  u16* qkv_bf = (u16*)(ws + 25165824);      // 50 MB
  u16* ctx_bf = (u16*)(ws + 75497472);      // 16 MB
  u16* vtg    = (u16*)(ws);                 // reuses x_bf region (16 MB)

  cvt_kernel<<<2048, 256, 0, stream>>>(x, x_bf, M * D / 4);
  cvt_kernel<<<1024, 256, 0, stream>>>(w1, w1_bf, N1 * D / 4);
  cvt_kernel<<<512, 256, 0, stream>>>(w2, w2_bf, D * D / 4);

  gemm_bt<0><<<dim3(N1 / 128, M / 128), 256, 0, stream>>>(
      x_bf, w1_bf, b1, qkv_bf, nullptr, nullptr, M, N1, D);

  vtrans_kernel<<<dim3(32, 16, 4), 256, 0, stream>>>(qkv_bf, vtg);

  // grid: x = b*16+h (64), y -> qi reversed (16); wg%8 == bh%8 (XCD locality)
  attn_kernel<<<dim3(64, 16), 256, 0, stream>>>(qkv_bf, vtg, ctx_bf);

  gemm_bt<1><<<dim3(D / 128, M / 128), 256, 0, stream>>>(
      ctx_bf, w2_bf, b2, nullptr, out, x, M, D, D);

  ln_kernel<<<M, 256, 0, stream>>>(out, gamma, beta);
}